// Round 13
// baseline (6326.585 us; speedup 1.0000x reference)
//
#include <hip/hip_runtime.h>

// KANSpikingNeuron — exact-arithmetic fast kernel, v2 (LDS swizzle fix).
// Arithmetic (proven r11, 33.5M sign-exact): per element, 8 flat K-blocks of
// 512 ascending; serial FMA chain per block; fp32 ascending merges; separate
// fp32 bias add; relu (fp32 h) / >0 threshold.
// r12 -> r13 change: W LDS fragment reads were ds_read_b128 with 2-addr/bank
// serialization (16B alignment forces it). Now 4x ds_read_b64 with
// even-residue swizzle f(tc)=tc*8+2*(tc>>2), stride 134 -> each b64's 16
// addresses hit 16 distinct even banks (+1 words fill odd banks) = 1 bank
// round per instruction = data floor. FMA order bit-identical.

constexpr int B_TOT = 8192, IN = 4096, HID = 4096, OUT = 4096;
constexpr int BM = 128, BN = 128, BK = 32;
constexpr int KBLK_TILES = 512 / BK;     // 16 tiles per 512-k block
constexpr int WS_STRIDE = 134;           // even stride, fits max f+7 = 133

// W word base per col-group c=0..15: even-residue-distinct mod 32.
__device__ __forceinline__ int wb(int c) { return c * 8 + 2 * (c >> 2); }

template <bool RELU_STORE>
__global__ __launch_bounds__(256, 2)
void gemm_exact(const float* __restrict__ A, const float* __restrict__ W,
                const float* __restrict__ bias, float* __restrict__ C,
                int N, int K) {
#pragma clang fp contract(off)
  __shared__ float As[BK][BM];          // k-major A tile
  __shared__ float Ws[BK * WS_STRIDE];  // k-major W tile, swizzled cols

  const int tid = threadIdx.x;
  const int tc = tid & 15;              // output col group (8 cols)
  const int tr = tid >> 4;              // output row group (8 rows)
  const int bm = blockIdx.y * BM;
  const int bn = blockIdx.x * BN;

  const int srow = tid >> 1;            // staging row 0..127
  const int kb   = (tid & 1) * 16;      // staging k-base within tile
  // write word for col srow: tc=srow>>3, j=srow&7 -> wb(tc)+j = srow + 2*(srow>>5)
  const int wwb  = srow + 2 * (srow >> 5);

  float tot[8][8], blk[8][8];
#pragma unroll
  for (int i = 0; i < 8; ++i)
#pragma unroll
    for (int j = 0; j < 8; ++j) { tot[i][j] = 0.0f; blk[i][j] = 0.0f; }

  const float* arow = A + (size_t)(bm + srow) * K + kb;
  const float* wrow = W + (size_t)(bn + srow) * K + kb;

  const int NT = K / BK;                // 128 tiles, ascending k
  for (int t = 0; t < NT; ++t) {
    // ---- issue global loads for tile t (4 float4 each of A, W) ----
    float4 av[4], wv[4];
#pragma unroll
    for (int u = 0; u < 4; ++u) {
      av[u] = *reinterpret_cast<const float4*>(arow + t * BK + 4 * u);
      wv[u] = *reinterpret_cast<const float4*>(wrow + t * BK + 4 * u);
    }
    // ---- 512-k block boundary: fold chain into total (exact order) ----
    if (t > 0 && (t % KBLK_TILES) == 0) {
#pragma unroll
      for (int i = 0; i < 8; ++i)
#pragma unroll
        for (int j = 0; j < 8; ++j) {
          tot[i][j] = __fadd_rn(tot[i][j], blk[i][j]);
          blk[i][j] = 0.0f;
        }
    }
    __syncthreads();   // previous tile's LDS reads complete
    // ---- LDS write, transposed to k-major ----
#pragma unroll
    for (int u = 0; u < 4; ++u) {
      const float va[4] = {av[u].x, av[u].y, av[u].z, av[u].w};
      const float vw[4] = {wv[u].x, wv[u].y, wv[u].z, wv[u].w};
#pragma unroll
      for (int e = 0; e < 4; ++e) {
        const int kk = kb + 4 * u + e;
        As[kk][srow] = va[e];
        Ws[kk * WS_STRIDE + wwb] = vw[e];
      }
    }
    __syncthreads();

    // ---- compute: 32 k-steps, 64 FMAs each, k strictly ascending ----
#pragma unroll 2
    for (int kk = 0; kk < BK; ++kk) {
      float a[8], w[8];
      *reinterpret_cast<float4*>(&a[0]) =
          *reinterpret_cast<const float4*>(&As[kk][tr * 8]);
      *reinterpret_cast<float4*>(&a[4]) =
          *reinterpret_cast<const float4*>(&As[kk][tr * 8 + 4]);
      const float* wp = &Ws[kk * WS_STRIDE + wb(tc)];
      // 4x ds_read_b64, each instruction 1 bank round (even-residue swizzle)
      float2 w01 = *reinterpret_cast<const float2*>(wp);
      float2 w23 = *reinterpret_cast<const float2*>(wp + 2);
      float2 w45 = *reinterpret_cast<const float2*>(wp + 4);
      float2 w67 = *reinterpret_cast<const float2*>(wp + 6);
      w[0] = w01.x; w[1] = w01.y; w[2] = w23.x; w[3] = w23.y;
      w[4] = w45.x; w[5] = w45.y; w[6] = w67.x; w[7] = w67.y;
#pragma unroll
      for (int i = 0; i < 8; ++i)
#pragma unroll
        for (int j = 0; j < 8; ++j)
          blk[i][j] = __fmaf_rn(a[i], w[j], blk[i][j]);
    }
  }

  // ---- final block fold + bias + epilogue (exact order) ----
  float bs[8];
#pragma unroll
  for (int j = 0; j < 8; ++j) bs[j] = bias[bn + tc * 8 + j];
#pragma unroll
  for (int i = 0; i < 8; ++i) {
    const size_t m = (size_t)(bm + tr * 8 + i);
    float o[8];
#pragma unroll
    for (int j = 0; j < 8; ++j) {
      float v = __fadd_rn(tot[i][j], blk[i][j]);   // last 512-block fold
      v = __fadd_rn(v, bs[j]);                     // separate bias add
      if constexpr (RELU_STORE)
        o[j] = v > 0.0f ? v : 0.0f;
      else
        o[j] = v > 0.0f ? 1.0f : 0.0f;
    }
    float* cp = C + m * N + bn + tc * 8;
    *reinterpret_cast<float4*>(cp)     = make_float4(o[0], o[1], o[2], o[3]);
    *reinterpret_cast<float4*>(cp + 4) = make_float4(o[4], o[5], o[6], o[7]);
  }
}

extern "C" void kernel_launch(void* const* d_in, const int* in_sizes, int n_in,
                              void* d_out, int out_size, void* d_ws, size_t ws_size,
                              hipStream_t stream) {
  const float* x  = (const float*)d_in[0];
  const float* W1 = (const float*)d_in[1];
  const float* b1 = (const float*)d_in[2];
  const float* W2 = (const float*)d_in[3];
  const float* b2 = (const float*)d_in[4];
  float* out = (float*)d_out;

  const dim3 blk(256);

  size_t rows = ws_size / ((size_t)HID * sizeof(float));
  rows = (rows / BM) * BM;
  if (rows > (size_t)B_TOT) rows = B_TOT;
  if (rows < BM) rows = BM;  // safety; ws known large
  float* h = (float*)d_ws;

  for (int m0 = 0; m0 < B_TOT; m0 += (int)rows) {
    const int mrows = (B_TOT - m0 < (int)rows) ? (B_TOT - m0) : (int)rows;
    const dim3 g1(HID / BN, mrows / BM);
    const dim3 g2(OUT / BN, mrows / BM);
    gemm_exact<true><<<g1, blk, 0, stream>>>(
        x + (size_t)m0 * IN, W1, b1, h, HID, IN);
    gemm_exact<false><<<g2, blk, 0, stream>>>(
        h, W2, b2, out + (size_t)m0 * OUT, OUT, HID);
  }
}

// Round 14
// 6175.307 us; speedup vs baseline: 1.0245x; 1.0245x over previous
//
#include <hip/hip_runtime.h>

// KANSpikingNeuron — exact-arithmetic, v3: K-block pass split + 8x16 acc.
// Proven chain (r11, 33.5M sign-exact): per element y = fadd(...fadd(fadd(
//   b0,b1),b2)...,b7) + bias, where b_p = serial FMA chain over k in
//   [512p, 512p+512) ascending; h fp32 relu; spike = y>0.
// The ascending merge IS a global fp32 RMW accumulate (fp32 ld/st exact):
//   pass0: P=b0 (store); pass p: P=fadd(P,b_p); pass7: y=fadd(fadd(P,b7),bias).
// Per pass: 128x256 tile, 256 thr, 8x16 acc (SINGLE set, 128 VGPR), BK=32,
// reg-prefetch staging (T14), chunk-interleaved W LDS (2-way reads = free).

constexpr int B_TOT = 8192, IN = 4096, HID = 4096, OUT = 4096;
constexpr int BM = 128, BN = 256, BK = 32;
constexpr int KBLK = 512;
constexpr int NT = KBLK / BK;   // 16 tiles per pass

// MODE: 0 = store blk; 1 = store fadd(prev, blk); 2 = final: bias + epilogue
template <int MODE, bool RELU>
__global__ __launch_bounds__(256, 2)
void gemm_pass(const float* __restrict__ A, const float* __restrict__ W,
               const float* __restrict__ bias, const float* Cprev,
               float* Cout, int N, int K, int k0) {
#pragma clang fp contract(off)
  __shared__ float As[BK][BM];      // 16 KB, k-major
  __shared__ float Ws[BK * BN];     // 32 KB, k-major, chunk-interleaved

  const int tid = threadIdx.x;
  const int tc = tid & 15;          // 16 cols of 16
  const int tr = tid >> 4;          // 16 rows of 8
  const int bm = blockIdx.y * BM;
  const int bn = blockIdx.x * BN;

  // staging: A -> thread (srow, kb) 16 floats; W -> thread row tid, 32 floats
  const int srow = tid >> 1;
  const int kb = (tid & 1) * 16;
  // W col c lives at word ((c>>2)&3)*64 + (c>>4)*4 + (c&3) within a k-row:
  // read (kk,q,tc) = float4 at kk*BN + q*64 + tc*4  (16 addrs, 2-way = free)
  const int cw = ((tid >> 2) & 3) * 64 + (tid >> 4) * 4 + (tid & 3);

  const float* arow = A + (size_t)(bm + srow) * K + (k0 + kb);
  const float* wrow = W + (size_t)(bn + tid) * K + k0;

  float4 av[4], wv[8];
#define PREFETCH(t)                                                        \
  {                                                                        \
    _Pragma("unroll") for (int u = 0; u < 4; ++u)                          \
        av[u] = *reinterpret_cast<const float4*>(arow + (t)*BK + 4 * u);   \
    _Pragma("unroll") for (int u = 0; u < 8; ++u)                          \
        wv[u] = *reinterpret_cast<const float4*>(wrow + (t)*BK + 4 * u);   \
  }
#define STAGE_WRITE()                                                      \
  {                                                                        \
    _Pragma("unroll") for (int u = 0; u < 4; ++u) {                        \
      const float va[4] = {av[u].x, av[u].y, av[u].z, av[u].w};            \
      _Pragma("unroll") for (int e = 0; e < 4; ++e)                        \
          As[kb + 4 * u + e][srow] = va[e];                                \
    }                                                                      \
    _Pragma("unroll") for (int u = 0; u < 8; ++u) {                        \
      const float vw[4] = {wv[u].x, wv[u].y, wv[u].z, wv[u].w};            \
      _Pragma("unroll") for (int e = 0; e < 4; ++e)                        \
          Ws[(4 * u + e) * BN + cw] = vw[e];                               \
    }                                                                      \
  }

  float blk[8][16];
#pragma unroll
  for (int i = 0; i < 8; ++i)
#pragma unroll
    for (int j = 0; j < 16; ++j) blk[i][j] = 0.0f;

  PREFETCH(0)
  STAGE_WRITE()
  __syncthreads();

  for (int t = 0; t < NT; ++t) {
    if (t + 1 < NT) PREFETCH(t + 1)        // HBM latency hides under compute
#pragma unroll 2
    for (int kk = 0; kk < BK; ++kk) {
      float a[8], w[16];
      *reinterpret_cast<float4*>(&a[0]) =
          *reinterpret_cast<const float4*>(&As[kk][tr * 8]);
      *reinterpret_cast<float4*>(&a[4]) =
          *reinterpret_cast<const float4*>(&As[kk][tr * 8 + 4]);
#pragma unroll
      for (int q = 0; q < 4; ++q)
        *reinterpret_cast<float4*>(&w[4 * q]) =
            *reinterpret_cast<const float4*>(&Ws[kk * BN + q * 64 + tc * 4]);
#pragma unroll
      for (int i = 0; i < 8; ++i)
#pragma unroll
        for (int j = 0; j < 16; ++j)
          blk[i][j] = __fmaf_rn(a[i], w[j], blk[i][j]);   // k ascending chain
    }
    __syncthreads();                        // all reads of this tile done
    if (t + 1 < NT) {
      STAGE_WRITE()
      __syncthreads();
    }
  }
#undef PREFETCH
#undef STAGE_WRITE

  // ---- epilogue ----
  float bs[16];
  if constexpr (MODE == 2) {
#pragma unroll
    for (int j = 0; j < 16; ++j) bs[j] = bias[bn + tc * 16 + j];
  }
#pragma unroll
  for (int i = 0; i < 8; ++i) {
    const size_t m = (size_t)(bm + tr * 8 + i);
    const size_t base = m * N + bn + tc * 16;
    float4 cv[4];
    if constexpr (MODE >= 1) {
#pragma unroll
      for (int q = 0; q < 4; ++q)
        cv[q] = *reinterpret_cast<const float4*>(Cprev + base + 4 * q);
    }
    float o[16];
#pragma unroll
    for (int j = 0; j < 16; ++j) {
      float v = blk[i][j];
      if constexpr (MODE >= 1) {
        const float pj = (&cv[j >> 2].x)[j & 3];
        v = __fadd_rn(pj, v);               // ascending block merge
      }
      if constexpr (MODE == 2) {
        v = __fadd_rn(v, bs[j]);            // separate fp32 bias add
        o[j] = RELU ? (v > 0.0f ? v : 0.0f) : (v > 0.0f ? 1.0f : 0.0f);
      } else {
        o[j] = v;                           // fp32 partial, exact
      }
    }
#pragma unroll
    for (int q = 0; q < 4; ++q)
      *reinterpret_cast<float4*>(Cout + base + 4 * q) =
          make_float4(o[4 * q], o[4 * q + 1], o[4 * q + 2], o[4 * q + 3]);
  }
}

static void run_layer(const float* A, const float* W, const float* bias,
                      float* partial, float* dest, bool relu, int rows,
                      int N, int K, hipStream_t stream) {
  const dim3 blk(256);
  const dim3 g(N / BN, rows / BM);
  const int NP = K / KBLK;   // 8 passes
  for (int p = 0; p < NP; ++p) {
    const int k0 = p * KBLK;
    if (p == 0) {
      gemm_pass<0, false><<<g, blk, 0, stream>>>(A, W, bias, nullptr, partial,
                                                 N, K, k0);
    } else if (p < NP - 1) {
      gemm_pass<1, false><<<g, blk, 0, stream>>>(A, W, bias, partial, partial,
                                                 N, K, k0);
    } else if (relu) {
      gemm_pass<2, true><<<g, blk, 0, stream>>>(A, W, bias, partial, dest,
                                                N, K, k0);
    } else {
      gemm_pass<2, false><<<g, blk, 0, stream>>>(A, W, bias, partial, dest,
                                                 N, K, k0);
    }
  }
}

extern "C" void kernel_launch(void* const* d_in, const int* in_sizes, int n_in,
                              void* d_out, int out_size, void* d_ws, size_t ws_size,
                              hipStream_t stream) {
  const float* x  = (const float*)d_in[0];
  const float* W1 = (const float*)d_in[1];
  const float* b1 = (const float*)d_in[2];
  const float* W2 = (const float*)d_in[3];
  const float* b2 = (const float*)d_in[4];
  float* out = (float*)d_out;

  // chunk rows so h + y2-partial fit in ws (ws is ~512MiB -> full 8192 rows)
  size_t rows = ws_size / ((size_t)2 * HID * sizeof(float));
  rows = (rows / BM) * BM;
  if (rows > (size_t)B_TOT) rows = B_TOT;
  if (rows < BM) rows = BM;

  float* h   = (float*)d_ws;                         // rows x HID
  float* y2p = h + (size_t)rows * HID;               // rows x OUT

  for (int m0 = 0; m0 < B_TOT; m0 += (int)rows) {
    const int mrows = (B_TOT - m0 < (int)rows) ? (B_TOT - m0) : (int)rows;
    // layer 1: h = relu(x @ W1^T + b1)   (h doubles as its own partial)
    run_layer(x + (size_t)m0 * IN, W1, b1, h, h, true, mrows, HID, IN, stream);
    // layer 2: out = (h @ W2^T + b2) > 0 (partial in y2p, final into out)
    run_layer(h, W2, b2, y2p, out + (size_t)m0 * OUT, false, mrows, OUT, HID,
              stream);
  }
}